// Round 4
// baseline (231.192 us; speedup 1.0000x reference)
//
#include <hip/hip_runtime.h>
#include <hip/hip_bf16.h>
#include <stdint.h>

// ---------- types ----------
typedef __attribute__((ext_vector_type(8))) short          bf16x8;
typedef __attribute__((ext_vector_type(4))) float          f32x4;
typedef __attribute__((ext_vector_type(4))) float          f4;
typedef __attribute__((ext_vector_type(8))) unsigned short u16x8;
typedef __attribute__((ext_vector_type(4))) unsigned short u16x4;

#define DEVINL __device__ __forceinline__

static constexpr int B  = 4;
static constexpr int S  = 4096;
static constexpr int D  = 256;
static constexpr int SP = 410;   // ceil(4096/10), SAME pooling, pad_lo = 2
static constexpr int KZ = 16;    // pv split-K factor
static constexpr int MO = B * SP;                 // 1640
static constexpr size_t PSLICE = (size_t)MO * D;  // 419840

DEVINL unsigned short f2bf(float x) {
  union { float f; unsigned u; } v; v.f = x;
  unsigned r = v.u + 0x7FFFu + ((v.u >> 16) & 1u);   // round-to-nearest-even
  return (unsigned short)(r >> 16);
}

DEVINL f32x4 mfma16(bf16x8 a, bf16x8 b, f32x4 c) {
  return __builtin_amdgcn_mfma_f32_16x16x32_bf16(a, b, c, 0, 0, 0);
}

typedef const __attribute__((address_space(1))) void* gas_t;
typedef __attribute__((address_space(3))) void*       las_t;
DEVINL void gload16(const void* g, void* l) {
  __builtin_amdgcn_global_load_lds((gas_t)g, (las_t)l, 16, 0, 0);
}

// counted-vmcnt pipeline helpers (T4): loads stay in flight across barriers
DEVINL void cfence() { asm volatile("" ::: "memory"); }
DEVINL void barrier_mem() { cfence(); __builtin_amdgcn_s_barrier(); cfence(); }
#define WAIT_VM(N) asm volatile("s_waitcnt vmcnt(" #N ")" ::: "memory")

// ---------- K0: transpose + convert the 4 weight matrices to bf16 [n][k] ----------
__global__ __launch_bounds__(256) void wt_trans_kernel(
    const float* __restrict__ wq, const float* __restrict__ wk,
    const float* __restrict__ wv, const float* __restrict__ wo,
    unsigned short* __restrict__ wt)
{
  int idx = blockIdx.x * 256 + threadIdx.x;   // 4 * 256 * 256
  int mat = idx >> 16;
  int r   = idx & 65535;
  int n   = r >> 8;
  int k   = r & 255;
  const float* w = (mat == 0) ? wq : (mat == 1) ? wk : (mat == 2) ? wv : wo;
  wt[idx] = f2bf(w[k * 256 + n]);             // wt[mat][n][k] = w[k][n]
}

// ---------- K0b: streaming f32 -> bf16 for q,k,v ----------
__global__ __launch_bounds__(256) void cvt_kernel(
    const float* __restrict__ xq, const float* __restrict__ xk, const float* __restrict__ xv,
    unsigned short* __restrict__ oq, unsigned short* __restrict__ ok, unsigned short* __restrict__ ov)
{
  int z = blockIdx.y;
  const float* x    = (z == 0) ? xq : (z == 1) ? xk : xv;
  unsigned short* o = (z == 0) ? oq : (z == 1) ? ok : ov;
  size_t i = ((size_t)blockIdx.x * 256 + threadIdx.x) * 8;
  f4 a = *reinterpret_cast<const f4*>(x + i);
  f4 c = *reinterpret_cast<const f4*>(x + i + 4);
  u16x8 h;
  h[0] = f2bf(a[0]); h[1] = f2bf(a[1]); h[2] = f2bf(a[2]); h[3] = f2bf(a[3]);
  h[4] = f2bf(c[0]); h[5] = f2bf(c[1]); h[6] = f2bf(c[2]); h[7] = f2bf(c[3]);
  *reinterpret_cast<u16x8*>(o + i) = h;
}

// ---------- K1: QKV projection GEMM (bf16, dbuf + counted vmcnt) ----------
__global__ __launch_bounds__(512) void proj_kernel(
    const unsigned short* __restrict__ xq, const unsigned short* __restrict__ xk,
    const unsigned short* __restrict__ xv, const unsigned short* __restrict__ wt,
    const float* __restrict__ bq, const float* __restrict__ bk, const float* __restrict__ bv,
    unsigned short* __restrict__ qp, unsigned short* __restrict__ kp, unsigned short* __restrict__ vp)
{
  int z = blockIdx.z;
  const unsigned short* X = (z == 0) ? xq : (z == 1) ? xk : xv;
  const unsigned short* W = wt + z * 65536;
  const float* bias       = (z == 0) ? bq : (z == 1) ? bk : bv;
  unsigned short* Out     = (z == 0) ? qp : (z == 1) ? kp : vp;

  int m0 = blockIdx.x * 256;
  int n0 = blockIdx.y * 128;

  __shared__ __align__(16) struct { char A[2][32768]; char Bm[2][16384]; } sm;

  const char* Xc = (const char*)X;
  const char* Wc = (const char*)W;

  int tid  = threadIdx.x;
  int lane = tid & 63, wid = tid >> 6;
  int wr = wid >> 1, wc = wid & 1;       // 4x2 waves, 64x64 each
  int lrow = lane & 15, kseg = lane >> 4;

  f32x4 zero4 = {0.f, 0.f, 0.f, 0.f};
  f32x4 acc[4][4];
#pragma unroll
  for (int i = 0; i < 4; i++)
#pragma unroll
    for (int j = 0; j < 4; j++) acc[i][j] = zero4;

  auto stage = [&](int t, int buf) {
#pragma unroll
    for (int i = 0; i < 4; ++i) {                   // A: 256 rows x 64k
      int inst = wid * 4 + i;
      int sg   = inst * 64 + lane;
      int row  = sg >> 3, c16 = sg & 7;
      gload16(Xc + ((size_t)(m0 + row) << 9) + (t << 7) + ((c16 ^ (row & 7)) << 4),
              sm.A[buf] + inst * 1024);
    }
#pragma unroll
    for (int i = 0; i < 2; ++i) {                   // B: 128 rows x 64k
      int inst = wid * 2 + i;
      int sg   = inst * 64 + lane;
      int row  = sg >> 3, c16 = sg & 7;
      gload16(Wc + ((size_t)(n0 + row) << 9) + (t << 7) + ((c16 ^ (row & 7)) << 4),
              sm.Bm[buf] + inst * 1024);
    }
  };

  stage(0, 0);
#pragma unroll
  for (int t = 0; t < 4; ++t) {
    int cur = t & 1;
    if (t < 3) { stage(t + 1, cur ^ 1); WAIT_VM(6); } else { WAIT_VM(0); }
    barrier_mem();
    const char* Asm = sm.A[cur];
    const char* Bsm = sm.Bm[cur];
#pragma unroll
    for (int kk = 0; kk < 2; ++kk) {
      bf16x8 af[4], bfr[4];
#pragma unroll
      for (int mi = 0; mi < 4; ++mi) {
        int R = wr * 64 + mi * 16 + lrow;
        int c16 = (kk * 4 + kseg) ^ (R & 7);
        af[mi] = *reinterpret_cast<const bf16x8*>(Asm + R * 128 + c16 * 16);
      }
#pragma unroll
      for (int cf = 0; cf < 4; ++cf) {
        int nl = wc * 64 + cf * 16 + lrow;
        int c16 = (kk * 4 + kseg) ^ (nl & 7);
        bfr[cf] = *reinterpret_cast<const bf16x8*>(Bsm + nl * 128 + c16 * 16);
      }
#pragma unroll
      for (int mi = 0; mi < 4; ++mi)
#pragma unroll
        for (int cf = 0; cf < 4; ++cf)
          acc[mi][cf] = mfma16(af[mi], bfr[cf], acc[mi][cf]);
    }
    barrier_mem();
  }

  int r4 = kseg * 4;
#pragma unroll
  for (int mi = 0; mi < 4; mi++)
#pragma unroll
    for (int cf = 0; cf < 4; cf++) {
      int n = n0 + wc * 64 + cf * 16 + lrow;
      float bv_ = bias[n];
#pragma unroll
      for (int r = 0; r < 4; r++) {
        int m = m0 + wr * 64 + mi * 16 + r4 + r;
        Out[(size_t)m * 256 + n] = f2bf(acc[mi][cf][r] + bv_);
      }
    }
}

// ---------- K2: scores GEMM + fused max-pool (dbuf + counted vmcnt) ----------
__global__ __launch_bounds__(512) void scores_pool_kernel(
    const unsigned short* __restrict__ qp, const unsigned short* __restrict__ kp,
    float* __restrict__ pooled)
{
  int b  = blockIdx.z;
  int wb = blockIdx.y;              // 0..16
  int nb = blockIdx.x;              // 0..31
  int w0 = wb * 25;
  int qb = w0 * 10 - 2;
  int n0 = nb * 128;
  int nwin = SP - w0; if (nwin > 25) nwin = 25;

  __shared__ __align__(16) union SM {
    struct { char A[2][32768]; char Bm[2][16384]; } st;
    float pm[9216];                                 // 128 pairs x stride 72 (f32)
  } sm;

  const char* qpc = (const char*)(qp + (size_t)b * S * 256);
  const char* kpc = (const char*)(kp + (size_t)b * S * 256);

  int tid  = threadIdx.x;
  int lane = tid & 63, wid = tid >> 6;
  int wr = wid >> 1, wc = wid & 1;       // 4x2 wave grid, each 64x64
  int lrow = lane & 15, kseg = lane >> 4;

  f32x4 zero4 = {0.f, 0.f, 0.f, 0.f};
  f32x4 acc[4][4];
#pragma unroll
  for (int i = 0; i < 4; i++)
#pragma unroll
    for (int j = 0; j < 4; j++) acc[i][j] = zero4;

  auto stage = [&](int t, int buf) {
#pragma unroll
    for (int i = 0; i < 4; ++i) {
      int inst = wid * 4 + i;
      int sg   = inst * 64 + lane;
      int row  = sg >> 3, c16 = sg & 7;
      int q = qb + row; q = (q < 0) ? 0 : ((q > S - 1) ? (S - 1) : q);
      gload16(qpc + ((size_t)q << 9) + (t << 7) + ((c16 ^ (row & 7)) << 4),
              sm.st.A[buf] + inst * 1024);
    }
#pragma unroll
    for (int i = 0; i < 2; ++i) {
      int inst = wid * 2 + i;
      int sg   = inst * 64 + lane;
      int row  = sg >> 3, c16 = sg & 7;
      gload16(kpc + ((size_t)(n0 + row) << 9) + (t << 7) + ((c16 ^ (row & 7)) << 4),
              sm.st.Bm[buf] + inst * 1024);
    }
  };

  stage(0, 0);
#pragma unroll
  for (int t = 0; t < 4; ++t) {
    int cur = t & 1;
    if (t < 3) { stage(t + 1, cur ^ 1); WAIT_VM(6); } else { WAIT_VM(0); }
    barrier_mem();
    const char* Asm = sm.st.A[cur];
    const char* Bsm = sm.st.Bm[cur];
#pragma unroll
    for (int kk = 0; kk < 2; ++kk) {
      bf16x8 af[4], bfr[4];
#pragma unroll
      for (int mi = 0; mi < 4; ++mi) {
        int R = wr * 64 + mi * 16 + lrow;
        int c16 = (kk * 4 + kseg) ^ (R & 7);
        af[mi] = *reinterpret_cast<const bf16x8*>(Asm + R * 128 + c16 * 16);
      }
#pragma unroll
      for (int cf = 0; cf < 4; ++cf) {
        int nl = wc * 64 + cf * 16 + lrow;
        int c16 = (kk * 4 + kseg) ^ (nl & 7);
        bfr[cf] = *reinterpret_cast<const bf16x8*>(Bsm + nl * 128 + c16 * 16);
      }
#pragma unroll
      for (int mi = 0; mi < 4; ++mi)
#pragma unroll
        for (int cf = 0; cf < 4; ++cf)
          acc[mi][cf] = mfma16(af[mi], bfr[cf], acc[mi][cf]);
    }
    barrier_mem();
  }

  // ---- pooling: in-register pair-max -> LDS [128 pairs][72] f32 -> 5-way window max
  int h = kseg;
#pragma unroll
  for (int c = 0; c < 2; ++c) {
    __syncthreads();
    if (wc == c) {
#pragma unroll
      for (int mi = 0; mi < 4; ++mi) {
        int p = wr * 32 + mi * 8 + h * 2;
#pragma unroll
        for (int cf = 0; cf < 4; ++cf) {
          int col = cf * 16 + lrow;
          sm.pm[p * 72 + col]       = fmaxf(acc[mi][cf][0], acc[mi][cf][1]);
          sm.pm[(p + 1) * 72 + col] = fmaxf(acc[mi][cf][2], acc[mi][cf][3]);
        }
      }
    }
    __syncthreads();
    for (int s = tid; s < 1600; s += 512) {
      int j = s >> 6, col = s & 63;
      if (j < nwin) {
        float m = -3.4e38f;
#pragma unroll
        for (int i = 0; i < 5; ++i) {
          int p  = 5 * j + i;
          int q0 = qb + 2 * p;
          if (q0 >= 0 && q0 < S) m = fmaxf(m, sm.pm[p * 72 + col]);
        }
        pooled[((size_t)b * SP + w0 + j) * 4096 + n0 + c * 64 + col] = m * 0.0625f;
      }
    }
  }
}

// ---------- K3: row softmax (4096 cols), fp32 in, bf16 out ----------
__global__ __launch_bounds__(256) void softmax_kernel(
    const float* __restrict__ pooled, unsigned short* __restrict__ attn)
{
  int row = blockIdx.x;
  const float* p = pooled + (size_t)row * 4096;
  unsigned short* a = attn + (size_t)row * 4096;
  int tid = threadIdx.x;
  int lane = tid & 63, wid = tid >> 6;

  f4 v[4];
  float mx = -3.4e38f;
#pragma unroll
  for (int i = 0; i < 4; i++) {
    v[i] = *reinterpret_cast<const f4*>(&p[i * 1024 + tid * 4]);
    mx = fmaxf(mx, fmaxf(fmaxf(v[i][0], v[i][1]), fmaxf(v[i][2], v[i][3])));
  }
#pragma unroll
  for (int off = 32; off > 0; off >>= 1) mx = fmaxf(mx, __shfl_xor(mx, off, 64));
  __shared__ float redm[4];
  __shared__ float reds[4];
  if (lane == 0) redm[wid] = mx;
  __syncthreads();
  mx = fmaxf(fmaxf(redm[0], redm[1]), fmaxf(redm[2], redm[3]));

  float e[16];
  float sum = 0.f;
#pragma unroll
  for (int i = 0; i < 4; i++)
#pragma unroll
    for (int j = 0; j < 4; j++) {
      float t = __expf(v[i][j] - mx);
      e[i * 4 + j] = t;
      sum += t;
    }
#pragma unroll
  for (int off = 32; off > 0; off >>= 1) sum += __shfl_xor(sum, off, 64);
  if (lane == 0) reds[wid] = sum;
  __syncthreads();
  sum = reds[0] + reds[1] + reds[2] + reds[3];
  float inv = 1.f / sum;
#pragma unroll
  for (int i = 0; i < 4; i++) {
    u16x4 o;
#pragma unroll
    for (int j = 0; j < 4; j++) o[j] = f2bf(e[i * 4 + j] * inv);
    *reinterpret_cast<u16x4*>(&a[i * 1024 + tid * 4]) = o;
  }
}

// ---------- K4a: transpose vp [b][k][d] -> vpT [b][d][k] ----------
__global__ __launch_bounds__(256) void vpt_kernel(
    const unsigned short* __restrict__ vp, unsigned short* __restrict__ vpT)
{
  int b  = blockIdx.y;
  int kt = blockIdx.x >> 2;
  int dt = blockIdx.x & 3;
  int k0 = kt * 64, d0 = dt * 64;

  __shared__ unsigned short t[64][66];
  const unsigned short* src = vp + (size_t)b * S * 256;
  unsigned short* dst = vpT + (size_t)b * 256 * S;

  int tid = threadIdx.x;
  for (int s = tid; s < 512; s += 256) {
    int r = s >> 3, seg = s & 7;
    u16x8 v = *reinterpret_cast<const u16x8*>(&src[(size_t)(k0 + r) * 256 + d0 + seg * 8]);
#pragma unroll
    for (int j = 0; j < 4; j++) {
      unsigned short* pp = &t[r][seg * 8 + j * 2];
      pp[0] = v[j * 2]; pp[1] = v[j * 2 + 1];
    }
  }
  __syncthreads();
  int d  = tid >> 2;
  int kb = (tid & 3) * 16;
  u16x8 o0, o1;
#pragma unroll
  for (int j = 0; j < 8; j++) o0[j] = t[kb + j][d];
#pragma unroll
  for (int j = 0; j < 8; j++) o1[j] = t[kb + 8 + j][d];
  *reinterpret_cast<u16x8*>(&dst[(size_t)(d0 + d) * S + k0 + kb])     = o0;
  *reinterpret_cast<u16x8*>(&dst[(size_t)(d0 + d) * S + k0 + kb + 8]) = o1;
}

// ---------- K4: PV GEMM, split-K=16, dbuf + counted vmcnt, partials to ws ----------
__global__ __launch_bounds__(256) void pv_kernel(
    const unsigned short* __restrict__ attn, const unsigned short* __restrict__ vpT,
    float* __restrict__ part)
{
  int bx = blockIdx.x;
  int b  = bx >> 2, mt = bx & 3;
  int m0 = mt * 128;
  int n0 = blockIdx.y * 128;
  int kz = blockIdx.z;
  int k0b = kz * 512;                  // byte offset of k-chunk start (256 k * 2B)

  const char* Ac = (const char*)(attn + (size_t)b * SP * 4096);
  const char* Bc = (const char*)(vpT  + (size_t)b * 256 * 4096);
  float* Pz = part + (size_t)kz * PSLICE;

  __shared__ __align__(16) struct { char A[2][16384]; char Bm[2][16384]; } sm;

  int tid  = threadIdx.x;
  int lane = tid & 63, wid = tid >> 6;
  int wr = wid >> 1, wc = wid & 1;      // 2x2 waves, 64x64
  int lrow = lane & 15, kseg = lane >> 4;

  f32x4 zero4 = {0.f, 0.f, 0.f, 0.f};
  f32x4 acc[4][4];
#pragma unroll
  for (int i = 0; i < 4; i++)
#pragma unroll
    for (int j = 0; j < 4; j++) acc[i][j] = zero4;

  auto stage = [&](int t, int buf) {
#pragma unroll
    for (int i = 0; i < 4; ++i) {                   // A: 128 rows x 64k (attn, row stride 8192B)
      int inst = wid * 4 + i;
      int sg   = inst * 64 + lane;
      int row  = sg >> 3, c16 = sg & 7;
      int m = m0 + row; m = (m > SP - 1) ? (SP - 1) : m;
      gload16(Ac + (size_t)m * 8192 + k0b + (t << 7) + ((c16 ^ (row & 7)) << 4),
              sm.A[buf] + inst * 1024);
    }
#pragma unroll
    for (int i = 0; i < 4; ++i) {                   // B: 128 rows x 64k (vpT, row stride 8192B)
      int inst = wid * 4 + i;
      int sg   = inst * 64 + lane;
      int row  = sg >> 3, c16 = sg & 7;
      gload16(Bc + (size_t)(n0 + row) * 8192 + k0b + (t << 7) + ((c16 ^ (row & 7)) << 4),
              sm.Bm[buf] + inst * 1024);
    }
  };

  stage(0, 0);
#pragma unroll
  for (int t = 0; t < 4; ++t) {
    int cur = t & 1;
    if (t < 3) { stage(t + 1, cur ^ 1); WAIT_VM(8); } else { WAIT_VM(0); }
    barrier_mem();
    const char* Asm = sm.A[cur];
    const char* Bsm = sm.Bm[cur];
#pragma unroll
    for (int kk = 0; kk < 2; ++kk) {
      bf16x8 af[4], bfr[4];
#pragma unroll
      for (int mi = 0; mi < 4; ++mi) {
        int R = wr * 64 + mi * 16 + lrow;
        int c16 = (kk * 4 + kseg) ^ (R & 7);
        af[mi] = *reinterpret_cast<const bf16x8*>(Asm + R * 128 + c16 * 16);
      }
#pragma unroll
      for (int cf = 0; cf < 4; ++cf) {
        int nl = wc * 64 + cf * 16 + lrow;
        int c16 = (kk * 4 + kseg) ^ (nl & 7);
        bfr[cf] = *reinterpret_cast<const bf16x8*>(Bsm + nl * 128 + c16 * 16);
      }
#pragma unroll
      for (int mi = 0; mi < 4; ++mi)
#pragma unroll
        for (int cf = 0; cf < 4; ++cf)
          acc[mi][cf] = mfma16(af[mi], bfr[cf], acc[mi][cf]);
    }
    barrier_mem();
  }

  int r4 = kseg * 4;
#pragma unroll
  for (int mi = 0; mi < 4; mi++)
#pragma unroll
    for (int cf = 0; cf < 4; cf++) {
      int n = n0 + wc * 64 + cf * 16 + lrow;
#pragma unroll
      for (int r = 0; r < 4; r++) {
        int m = m0 + wr * 64 + mi * 16 + r4 + r;
        if (m < SP) Pz[((size_t)b * SP + m) * 256 + n] = acc[mi][cf][r];
      }
    }
}

// ---------- K4b: sum 16 partials -> ctx bf16 ----------
__global__ __launch_bounds__(256) void reduce_kernel(
    const float* __restrict__ part, unsigned short* __restrict__ ctxb)
{
  size_t i = (size_t)blockIdx.x * 256 + threadIdx.x;   // PSLICE elements
  float s = 0.f;
#pragma unroll
  for (int z = 0; z < KZ; ++z) s += part[z * PSLICE + i];
  ctxb[i] = f2bf(s);
}

// ---------- K5: out = ctx @ wo + bo (fp32 out), dbuf + counted vmcnt ----------
__global__ __launch_bounds__(512) void out_kernel(
    const unsigned short* __restrict__ ctxb, const unsigned short* __restrict__ woT,
    const float* __restrict__ bo, float* __restrict__ out)
{
  int m0 = blockIdx.x * 256;           // over MO=1640
  int n0 = blockIdx.y * 128;

  __shared__ __align__(16) struct { char A[2][32768]; char Bm[2][16384]; } sm;

  const char* Xc = (const char*)ctxb;
  const char* Wc = (const char*)woT;

  int tid  = threadIdx.x;
  int lane = tid & 63, wid = tid >> 6;
  int wr = wid >> 1, wc = wid & 1;
  int lrow = lane & 15, kseg = lane >> 4;

  f32x4 zero4 = {0.f, 0.f, 0.f, 0.f};
  f32x4 acc[4][4];
#pragma unroll
  for (int i = 0; i < 4; i++)
#pragma unroll
    for (int j = 0; j < 4; j++) acc[i][j] = zero4;

  auto stage = [&](int t, int buf) {
#pragma unroll
    for (int i = 0; i < 4; ++i) {
      int inst = wid * 4 + i;
      int sg   = inst * 64 + lane;
      int row  = sg >> 3, c16 = sg & 7;
      int m = m0 + row; m = (m > MO - 1) ? (MO - 1) : m;
      gload16(Xc + ((size_t)m << 9) + (t << 7) + ((c16 ^ (row & 7)) << 4),
              sm.A[buf] + inst * 1024);
    }
#pragma unroll
    for (int i = 0; i < 2; ++i) {
      int inst = wid * 2 + i;
      int sg   = inst * 64 + lane;
      int row  = sg >> 3, c16 = sg & 7;
      gload16(Wc + ((size_t)(n0 + row) << 9) + (t << 7) + ((c16 ^ (row & 7)) << 4),
              sm.Bm[buf] + inst * 1024);
    }
  };

  stage(0, 0);
#pragma unroll
  for (int t = 0; t < 4; ++t) {
    int cur = t & 1;
    if (t < 3) { stage(t + 1, cur ^ 1); WAIT_VM(6); } else { WAIT_VM(0); }
    barrier_mem();
    const char* Asm = sm.A[cur];
    const char* Bsm = sm.Bm[cur];
#pragma unroll
    for (int kk = 0; kk < 2; ++kk) {
      bf16x8 af[4], bfr[4];
#pragma unroll
      for (int mi = 0; mi < 4; ++mi) {
        int R = wr * 64 + mi * 16 + lrow;
        int c16 = (kk * 4 + kseg) ^ (R & 7);
        af[mi] = *reinterpret_cast<const bf16x8*>(Asm + R * 128 + c16 * 16);
      }
#pragma unroll
      for (int cf = 0; cf < 4; ++cf) {
        int nl = wc * 64 + cf * 16 + lrow;
        int c16 = (kk * 4 + kseg) ^ (nl & 7);
        bfr[cf] = *reinterpret_cast<const bf16x8*>(Bsm + nl * 128 + c16 * 16);
      }
#pragma unroll
      for (int mi = 0; mi < 4; ++mi)
#pragma unroll
        for (int cf = 0; cf < 4; ++cf)
          acc[mi][cf] = mfma16(af[mi], bfr[cf], acc[mi][cf]);
    }
    barrier_mem();
  }

  int r4 = kseg * 4;
#pragma unroll
  for (int mi = 0; mi < 4; mi++)
#pragma unroll
    for (int cf = 0; cf < 4; cf++) {
      int n = n0 + wc * 64 + cf * 16 + lrow;
      float bv_ = bo[n];
#pragma unroll
      for (int r = 0; r < 4; r++) {
        int m = m0 + wr * 64 + mi * 16 + r4 + r;
        if (m < MO) out[(size_t)m * 256 + n] = acc[mi][cf][r] + bv_;
      }
    }
}

// ---------- launch ----------
extern "C" void kernel_launch(void* const* d_in, const int* in_sizes, int n_in,
                              void* d_out, int out_size, void* d_ws, size_t ws_size,
                              hipStream_t stream)
{
  const float* v  = (const float*)d_in[0];
  const float* k  = (const float*)d_in[1];
  const float* q  = (const float*)d_in[2];
  const float* wq = (const float*)d_in[3];
  const float* bq = (const float*)d_in[4];
  const float* wk = (const float*)d_in[5];
  const float* bk = (const float*)d_in[6];
  const float* wv = (const float*)d_in[7];
  const float* bv = (const float*)d_in[8];
  const float* wo = (const float*)d_in[9];
  const float* bo = (const float*)d_in[10];
  float* out = (float*)d_out;

  char* ws = (char*)d_ws;
  size_t off = 0;
  auto alloc = [&](size_t bytes) -> void* {
    void* p = ws + off;
    off += (bytes + 255) & ~(size_t)255;
    return p;
  };
  unsigned short* qp   = (unsigned short*)alloc((size_t)B * S * D * 2);     // 8 MB
  unsigned short* kp   = (unsigned short*)alloc((size_t)B * S * D * 2);     // 8 MB
  unsigned short* vp   = (unsigned short*)alloc((size_t)B * S * D * 2);     // 8 MB
  unsigned short* vpT  = (unsigned short*)alloc((size_t)B * S * D * 2);     // 8 MB
  unsigned short* wt   = (unsigned short*)alloc((size_t)4 * 256 * 256 * 2); // 0.5 MB
  unsigned short* ctxb = (unsigned short*)alloc(PSLICE * 2);                // 0.84 MB
  // shared region (disjoint lifetimes): qx/kx/vx [cvt->proj], pooled [scores->softmax],
  // part [pv->reduce]
  char* shared_region  = (char*)alloc((size_t)B * SP * 4096 * 4);
  unsigned short* attn = (unsigned short*)alloc((size_t)B * SP * 4096 * 2); // 13.4 MB

  unsigned short* qx = (unsigned short*)shared_region;
  unsigned short* kx = qx + (size_t)B * S * D;
  unsigned short* vx = kx + (size_t)B * S * D;
  float* pooled = (float*)shared_region;
  float* part   = (float*)shared_region;

  wt_trans_kernel<<<1024, 256, 0, stream>>>(wq, wk, wv, wo, wt);
  cvt_kernel<<<dim3(2048, 3), 256, 0, stream>>>(q, k, v, qx, kx, vx);
  proj_kernel<<<dim3(64, 2, 3), 512, 0, stream>>>(qx, kx, vx, wt, bq, bk, bv, qp, kp, vp);
  scores_pool_kernel<<<dim3(32, 17, 4), 512, 0, stream>>>(qp, kp, pooled);
  softmax_kernel<<<B * SP, 256, 0, stream>>>(pooled, attn);
  vpt_kernel<<<dim3(256, 4), 256, 0, stream>>>(vp, vpT);
  pv_kernel<<<dim3(16, 2, KZ), 256, 0, stream>>>(attn, vpT, part);
  reduce_kernel<<<(int)(PSLICE / 256), 256, 0, stream>>>(part, ctxb);
  out_kernel<<<dim3(7, 2), 512, 0, stream>>>(ctxb, wt + 3 * 65536, bo, out);
}

// Round 5
// 221.911 us; speedup vs baseline: 1.0418x; 1.0418x over previous
//
#include <hip/hip_runtime.h>
#include <hip/hip_bf16.h>
#include <stdint.h>

// ---------- types ----------
typedef __attribute__((ext_vector_type(8))) short          bf16x8;
typedef __attribute__((ext_vector_type(4))) float          f32x4;
typedef __attribute__((ext_vector_type(4))) float          f4;
typedef __attribute__((ext_vector_type(8))) unsigned short u16x8;
typedef __attribute__((ext_vector_type(4))) unsigned short u16x4;

#define DEVINL __device__ __forceinline__

static constexpr int B  = 4;
static constexpr int S  = 4096;
static constexpr int D  = 256;
static constexpr int SP = 410;   // ceil(4096/10), SAME pooling, pad_lo = 2
static constexpr int KZ = 16;    // pv split-K factor
static constexpr int MO = B * SP;                 // 1640
static constexpr size_t PSLICE = (size_t)MO * D;  // 419840

DEVINL unsigned short f2bf(float x) {
  union { float f; unsigned u; } v; v.f = x;
  unsigned r = v.u + 0x7FFFu + ((v.u >> 16) & 1u);   // round-to-nearest-even
  return (unsigned short)(r >> 16);
}

DEVINL f32x4 mfma16(bf16x8 a, bf16x8 b, f32x4 c) {
  return __builtin_amdgcn_mfma_f32_16x16x32_bf16(a, b, c, 0, 0, 0);
}

typedef const __attribute__((address_space(1))) void* gas_t;
typedef __attribute__((address_space(3))) void*       las_t;
DEVINL void gload16(const void* g, void* l) {
  __builtin_amdgcn_global_load_lds((gas_t)g, (las_t)l, 16, 0, 0);
}

// counted-vmcnt pipeline helpers: loads stay in flight across barriers
DEVINL void cfence() { asm volatile("" ::: "memory"); }
DEVINL void barrier_mem() { cfence(); __builtin_amdgcn_s_barrier(); cfence(); }
// raw barrier + LDS fence (does NOT drain vmcnt -> in-flight global_load_lds survive)
DEVINL void lds_barrier() {
  asm volatile("s_waitcnt lgkmcnt(0)" ::: "memory");
  __builtin_amdgcn_s_barrier();
  cfence();
}
#define WAIT_VM(N) asm volatile("s_waitcnt vmcnt(" #N ")" ::: "memory")

// ---------- K0: fused weight transpose (z==3) + streaming qkv f32->bf16 (z<3) ----------
__global__ __launch_bounds__(256) void cvtwt_kernel(
    const float* __restrict__ xq, const float* __restrict__ xk, const float* __restrict__ xv,
    const float* __restrict__ wq, const float* __restrict__ wk,
    const float* __restrict__ wv, const float* __restrict__ wo,
    unsigned short* __restrict__ oq, unsigned short* __restrict__ ok, unsigned short* __restrict__ ov,
    unsigned short* __restrict__ wt)
{
  int z = blockIdx.y;
  if (z == 3) {
    if (blockIdx.x >= 1024) return;
    int idx = blockIdx.x * 256 + threadIdx.x;   // 4 * 256 * 256
    int mat = idx >> 16;
    int r   = idx & 65535;
    int n   = r >> 8;
    int k   = r & 255;
    const float* w = (mat == 0) ? wq : (mat == 1) ? wk : (mat == 2) ? wv : wo;
    wt[idx] = f2bf(w[k * 256 + n]);             // wt[mat][n][k] = w[k][n]
    return;
  }
  const float* x    = (z == 0) ? xq : (z == 1) ? xk : xv;
  unsigned short* o = (z == 0) ? oq : (z == 1) ? ok : ov;
  size_t i = ((size_t)blockIdx.x * 256 + threadIdx.x) * 8;
  f4 a = *reinterpret_cast<const f4*>(x + i);
  f4 c = *reinterpret_cast<const f4*>(x + i + 4);
  u16x8 h;
  h[0] = f2bf(a[0]); h[1] = f2bf(a[1]); h[2] = f2bf(a[2]); h[3] = f2bf(a[3]);
  h[4] = f2bf(c[0]); h[5] = f2bf(c[1]); h[6] = f2bf(c[2]); h[7] = f2bf(c[3]);
  *reinterpret_cast<u16x8*>(o + i) = h;
}

// ---------- K1: QKV projection GEMM (bf16, dbuf + counted vmcnt) ----------
// z==2 writes vpT[b][d][s] directly (transposed epilogue) -> vpt kernel eliminated
__global__ __launch_bounds__(512) void proj_kernel(
    const unsigned short* __restrict__ xq, const unsigned short* __restrict__ xk,
    const unsigned short* __restrict__ xv, const unsigned short* __restrict__ wt,
    const float* __restrict__ bq, const float* __restrict__ bk, const float* __restrict__ bv,
    unsigned short* __restrict__ qp, unsigned short* __restrict__ kp, unsigned short* __restrict__ vpT)
{
  int z = blockIdx.z;
  const unsigned short* X = (z == 0) ? xq : (z == 1) ? xk : xv;
  const unsigned short* W = wt + z * 65536;
  const float* bias       = (z == 0) ? bq : (z == 1) ? bk : bv;

  int m0 = blockIdx.x * 256;
  int n0 = blockIdx.y * 128;

  __shared__ __align__(16) struct { char A[2][32768]; char Bm[2][16384]; } sm;

  const char* Xc = (const char*)X;
  const char* Wc = (const char*)W;

  int tid  = threadIdx.x;
  int lane = tid & 63, wid = tid >> 6;
  int wr = wid >> 1, wc = wid & 1;       // 4x2 waves, 64x64 each
  int lrow = lane & 15, kseg = lane >> 4;

  f32x4 zero4 = {0.f, 0.f, 0.f, 0.f};
  f32x4 acc[4][4];
#pragma unroll
  for (int i = 0; i < 4; i++)
#pragma unroll
    for (int j = 0; j < 4; j++) acc[i][j] = zero4;

  auto stage = [&](int t, int buf) {
#pragma unroll
    for (int i = 0; i < 4; ++i) {                   // A: 256 rows x 64k
      int inst = wid * 4 + i;
      int sg   = inst * 64 + lane;
      int row  = sg >> 3, c16 = sg & 7;
      gload16(Xc + ((size_t)(m0 + row) << 9) + (t << 7) + ((c16 ^ (row & 7)) << 4),
              sm.A[buf] + inst * 1024);
    }
#pragma unroll
    for (int i = 0; i < 2; ++i) {                   // B: 128 rows x 64k
      int inst = wid * 2 + i;
      int sg   = inst * 64 + lane;
      int row  = sg >> 3, c16 = sg & 7;
      gload16(Wc + ((size_t)(n0 + row) << 9) + (t << 7) + ((c16 ^ (row & 7)) << 4),
              sm.Bm[buf] + inst * 1024);
    }
  };

  stage(0, 0);
#pragma unroll
  for (int t = 0; t < 4; ++t) {
    int cur = t & 1;
    if (t < 3) { stage(t + 1, cur ^ 1); WAIT_VM(6); } else { WAIT_VM(0); }
    barrier_mem();
    const char* Asm = sm.A[cur];
    const char* Bsm = sm.Bm[cur];
#pragma unroll
    for (int kk = 0; kk < 2; ++kk) {
      bf16x8 af[4], bfr[4];
#pragma unroll
      for (int mi = 0; mi < 4; ++mi) {
        int R = wr * 64 + mi * 16 + lrow;
        int c16 = (kk * 4 + kseg) ^ (R & 7);
        af[mi] = *reinterpret_cast<const bf16x8*>(Asm + R * 128 + c16 * 16);
      }
#pragma unroll
      for (int cf = 0; cf < 4; ++cf) {
        int nl = wc * 64 + cf * 16 + lrow;
        int c16 = (kk * 4 + kseg) ^ (nl & 7);
        bfr[cf] = *reinterpret_cast<const bf16x8*>(Bsm + nl * 128 + c16 * 16);
      }
#pragma unroll
      for (int mi = 0; mi < 4; ++mi)
#pragma unroll
        for (int cf = 0; cf < 4; ++cf)
          acc[mi][cf] = mfma16(af[mi], bfr[cf], acc[mi][cf]);
    }
    barrier_mem();
  }

  int r4 = kseg * 4;
  if (z < 2) {
    unsigned short* Out = (z == 0) ? qp : kp;
#pragma unroll
    for (int mi = 0; mi < 4; mi++)
#pragma unroll
      for (int cf = 0; cf < 4; cf++) {
        int n = n0 + wc * 64 + cf * 16 + lrow;
        float bv_ = bias[n];
#pragma unroll
        for (int r = 0; r < 4; r++) {
          int m = m0 + wr * 64 + mi * 16 + r4 + r;
          Out[(size_t)m * 256 + n] = f2bf(acc[mi][cf][r] + bv_);
        }
      }
  } else {
    // transposed store: vpT[b][n][s], 4 consecutive s per lane = one 8B store
#pragma unroll
    for (int mi = 0; mi < 4; mi++)
#pragma unroll
      for (int cf = 0; cf < 4; cf++) {
        int n = n0 + wc * 64 + cf * 16 + lrow;
        float bv_ = bias[n];
        u16x4 hh;
#pragma unroll
        for (int r = 0; r < 4; r++) hh[r] = f2bf(acc[mi][cf][r] + bv_);
        int m  = m0 + wr * 64 + mi * 16 + r4;   // 4 consecutive rows
        int bb = m >> 12, s = m & 4095;
        *reinterpret_cast<u16x4*>(&vpT[(size_t)bb * (256 * 4096) + (size_t)n * 4096 + s]) = hh;
      }
  }
}

// ---------- K2: persistent scores GEMM + fused max-pool (v3) ----------
// grid = 256 blocks: (nb 0..31) x (b 0..3) x (half 0..1); each block walks 8-9
// q-window tiles with resident B (kp 128 rows x 256k = 64KB), A dbuf 2x32KB,
// continuous counted-vmcnt pipeline across tiles; pooling scratch overlays dead A[1].
__global__ __launch_bounds__(512) void scores_pool_kernel(
    const unsigned short* __restrict__ qp, const unsigned short* __restrict__ kp,
    float* __restrict__ pooled)
{
  int id   = blockIdx.x;
  int nb   = id & 31;
  int b    = (id >> 5) & 3;
  int half = id >> 7;
  int wb0  = half ? 9 : 0;
  int nwb  = half ? 8 : 9;
  int n0   = nb * 128;

  __shared__ __align__(16) struct { char A[2][32768]; char Bm[65536]; } sm;
  float* pm = (float*)sm.A[1];       // pooling scratch overlays dead A-half

  const char* qpc = (const char*)(qp + (size_t)b * S * 256);
  const char* kpc = (const char*)(kp + (size_t)b * S * 256);

  int tid  = threadIdx.x;
  int lane = tid & 63, wid = tid >> 6;
  int wr = wid >> 1, wc = wid & 1;       // 4x2 wave grid, each 64x64
  int lrow = lane & 15, kseg = lane >> 4;
  int h = kseg;

  // stage resident B: 128 rows x 256 k = 64KB, 8 insts/wave
#pragma unroll
  for (int i = 0; i < 8; ++i) {
    int inst = wid * 8 + i;
    int sg   = inst * 64 + lane;
    int row  = sg >> 5, c16 = sg & 31;
    gload16(kpc + ((size_t)(n0 + row) << 9) + (((size_t)(c16 ^ (row & 7))) << 4),
            sm.Bm + inst * 1024);
  }

  auto stageA = [&](int qbt, int ks, int buf) {
#pragma unroll
    for (int i = 0; i < 4; ++i) {
      int inst = wid * 4 + i;
      int sg   = inst * 64 + lane;
      int row  = sg >> 3, c16 = sg & 7;
      int q = qbt + row; q = (q < 0) ? 0 : ((q > S - 1) ? (S - 1) : q);
      gload16(qpc + ((size_t)q << 9) + (ks << 7) + ((c16 ^ (row & 7)) << 4),
              sm.A[buf] + inst * 1024);
    }
  };

  // prologue: stage A for tile 0, K-step 0 -> buf 0
  stageA(wb0 * 250 - 2, 0, 0);

  int gmax = nwb * 4;
  for (int i = 0; i < nwb; ++i) {
    int wb = wb0 + i, w0 = wb * 25;
    int qb = w0 * 10 - 2;
    int nwin = SP - w0; if (nwin > 25) nwin = 25;

    f32x4 zero4 = {0.f, 0.f, 0.f, 0.f};
    f32x4 acc[4][4];
#pragma unroll
    for (int mi = 0; mi < 4; mi++)
#pragma unroll
      for (int cf = 0; cf < 4; cf++) acc[mi][cf] = zero4;

#pragma unroll
    for (int ks = 0; ks < 4; ++ks) {
      int g  = (i << 2) | ks;
      int gn = g + 1;
      if (gn < gmax) {
        int i2 = gn >> 2, ks2 = gn & 3;
        stageA((wb0 + i2) * 250 - 2, ks2, gn & 1);
        WAIT_VM(4);
      } else {
        WAIT_VM(0);
      }
      barrier_mem();
      const char* Asm = sm.A[g & 1];
#pragma unroll
      for (int kk = 0; kk < 2; ++kk) {
        bf16x8 af[4], bfr[4];
#pragma unroll
        for (int mi = 0; mi < 4; ++mi) {
          int R = wr * 64 + mi * 16 + lrow;
          int c16 = (kk * 4 + kseg) ^ (R & 7);
          af[mi] = *reinterpret_cast<const bf16x8*>(Asm + R * 128 + c16 * 16);
        }
#pragma unroll
        for (int cf = 0; cf < 4; ++cf) {
          int nl = wc * 64 + cf * 16 + lrow;
          int c16 = ((ks << 3) + kk * 4 + kseg) ^ (nl & 7);
          bfr[cf] = *reinterpret_cast<const bf16x8*>(sm.Bm + nl * 512 + c16 * 16);
        }
#pragma unroll
        for (int mi = 0; mi < 4; ++mi)
#pragma unroll
          for (int cf = 0; cf < 4; ++cf)
            acc[mi][cf] = mfma16(af[mi], bfr[cf], acc[mi][cf]);
      }
      barrier_mem();
    }

    // ---- pooling: pair-max -> pm (A[1], stride 64 f32) -> 5-way window max
    // next tile's K-step-0 stage (targeting A[0]) stays in flight underneath.
#pragma unroll
    for (int c = 0; c < 2; ++c) {
      if (wc == c) {
#pragma unroll
        for (int mi = 0; mi < 4; ++mi) {
          int p = wr * 32 + mi * 8 + h * 2;
#pragma unroll
          for (int cf = 0; cf < 4; ++cf) {
            int col = cf * 16 + lrow;
            pm[p * 64 + col]       = fmaxf(acc[mi][cf][0], acc[mi][cf][1]);
            pm[(p + 1) * 64 + col] = fmaxf(acc[mi][cf][2], acc[mi][cf][3]);
          }
        }
      }
      lds_barrier();
      for (int s = tid; s < 1600; s += 512) {
        int j = s >> 6, col = s & 63;
        if (j < nwin) {
          float m = -3.4e38f;
#pragma unroll
          for (int t5 = 0; t5 < 5; ++t5) {
            int p  = 5 * j + t5;
            int q0 = qb + 2 * p;
            if (q0 >= 0 && q0 < S) m = fmaxf(m, pm[p * 64 + col]);
          }
          pooled[((size_t)b * SP + w0 + j) * 4096 + n0 + c * 64 + col] = m * 0.0625f;
        }
      }
      lds_barrier();
    }
  }
}

// ---------- K3: row softmax (4096 cols), fp32 in, bf16 out ----------
__global__ __launch_bounds__(256) void softmax_kernel(
    const float* __restrict__ pooled, unsigned short* __restrict__ attn)
{
  int row = blockIdx.x;
  const float* p = pooled + (size_t)row * 4096;
  unsigned short* a = attn + (size_t)row * 4096;
  int tid = threadIdx.x;
  int lane = tid & 63, wid = tid >> 6;

  f4 v[4];
  float mx = -3.4e38f;
#pragma unroll
  for (int i = 0; i < 4; i++) {
    v[i] = *reinterpret_cast<const f4*>(&p[i * 1024 + tid * 4]);
    mx = fmaxf(mx, fmaxf(fmaxf(v[i][0], v[i][1]), fmaxf(v[i][2], v[i][3])));
  }
#pragma unroll
  for (int off = 32; off > 0; off >>= 1) mx = fmaxf(mx, __shfl_xor(mx, off, 64));
  __shared__ float redm[4];
  __shared__ float reds[4];
  if (lane == 0) redm[wid] = mx;
  __syncthreads();
  mx = fmaxf(fmaxf(redm[0], redm[1]), fmaxf(redm[2], redm[3]));

  float e[16];
  float sum = 0.f;
#pragma unroll
  for (int i = 0; i < 4; i++)
#pragma unroll
    for (int j = 0; j < 4; j++) {
      float t = __expf(v[i][j] - mx);
      e[i * 4 + j] = t;
      sum += t;
    }
#pragma unroll
  for (int off = 32; off > 0; off >>= 1) sum += __shfl_xor(sum, off, 64);
  if (lane == 0) reds[wid] = sum;
  __syncthreads();
  sum = reds[0] + reds[1] + reds[2] + reds[3];
  float inv = 1.f / sum;
#pragma unroll
  for (int i = 0; i < 4; i++) {
    u16x4 o;
#pragma unroll
    for (int j = 0; j < 4; j++) o[j] = f2bf(e[i * 4 + j] * inv);
    *reinterpret_cast<u16x4*>(&a[i * 1024 + tid * 4]) = o;
  }
}

// ---------- K4: PV GEMM, split-K=16, dbuf + counted vmcnt, partials to ws ----------
__global__ __launch_bounds__(256) void pv_kernel(
    const unsigned short* __restrict__ attn, const unsigned short* __restrict__ vpT,
    float* __restrict__ part)
{
  int bx = blockIdx.x;
  int b  = bx >> 2, mt = bx & 3;
  int m0 = mt * 128;
  int n0 = blockIdx.y * 128;
  int kz = blockIdx.z;
  int k0b = kz * 512;                  // byte offset of k-chunk start (256 k * 2B)

  const char* Ac = (const char*)(attn + (size_t)b * SP * 4096);
  const char* Bc = (const char*)(vpT  + (size_t)b * 256 * 4096);
  float* Pz = part + (size_t)kz * PSLICE;

  __shared__ __align__(16) struct { char A[2][16384]; char Bm[2][16384]; } sm;

  int tid  = threadIdx.x;
  int lane = tid & 63, wid = tid >> 6;
  int wr = wid >> 1, wc = wid & 1;      // 2x2 waves, 64x64
  int lrow = lane & 15, kseg = lane >> 4;

  f32x4 zero4 = {0.f, 0.f, 0.f, 0.f};
  f32x4 acc[4][4];
#pragma unroll
  for (int i = 0; i < 4; i++)
#pragma unroll
    for (int j = 0; j < 4; j++) acc[i][j] = zero4;

  auto stage = [&](int t, int buf) {
#pragma unroll
    for (int i = 0; i < 4; ++i) {                   // A: 128 rows x 64k (attn, row stride 8192B)
      int inst = wid * 4 + i;
      int sg   = inst * 64 + lane;
      int row  = sg >> 3, c16 = sg & 7;
      int m = m0 + row; m = (m > SP - 1) ? (SP - 1) : m;
      gload16(Ac + (size_t)m * 8192 + k0b + (t << 7) + ((c16 ^ (row & 7)) << 4),
              sm.A[buf] + inst * 1024);
    }
#pragma unroll
    for (int i = 0; i < 4; ++i) {                   // B: 128 rows x 64k (vpT, row stride 8192B)
      int inst = wid * 4 + i;
      int sg   = inst * 64 + lane;
      int row  = sg >> 3, c16 = sg & 7;
      gload16(Bc + (size_t)(n0 + row) * 8192 + k0b + (t << 7) + ((c16 ^ (row & 7)) << 4),
              sm.Bm[buf] + inst * 1024);
    }
  };

  stage(0, 0);
#pragma unroll
  for (int t = 0; t < 4; ++t) {
    int cur = t & 1;
    if (t < 3) { stage(t + 1, cur ^ 1); WAIT_VM(8); } else { WAIT_VM(0); }
    barrier_mem();
    const char* Asm = sm.A[cur];
    const char* Bsm = sm.Bm[cur];
#pragma unroll
    for (int kk = 0; kk < 2; ++kk) {
      bf16x8 af[4], bfr[4];
#pragma unroll
      for (int mi = 0; mi < 4; ++mi) {
        int R = wr * 64 + mi * 16 + lrow;
        int c16 = (kk * 4 + kseg) ^ (R & 7);
        af[mi] = *reinterpret_cast<const bf16x8*>(Asm + R * 128 + c16 * 16);
      }
#pragma unroll
      for (int cf = 0; cf < 4; ++cf) {
        int nl = wc * 64 + cf * 16 + lrow;
        int c16 = (kk * 4 + kseg) ^ (nl & 7);
        bfr[cf] = *reinterpret_cast<const bf16x8*>(Bsm + nl * 128 + c16 * 16);
      }
#pragma unroll
      for (int mi = 0; mi < 4; ++mi)
#pragma unroll
        for (int cf = 0; cf < 4; ++cf)
          acc[mi][cf] = mfma16(af[mi], bfr[cf], acc[mi][cf]);
    }
    barrier_mem();
  }

  int r4 = kseg * 4;
#pragma unroll
  for (int mi = 0; mi < 4; mi++)
#pragma unroll
    for (int cf = 0; cf < 4; cf++) {
      int n = n0 + wc * 64 + cf * 16 + lrow;
#pragma unroll
      for (int r = 0; r < 4; r++) {
        int m = m0 + wr * 64 + mi * 16 + r4 + r;
        if (m < SP) Pz[((size_t)b * SP + m) * 256 + n] = acc[mi][cf][r];
      }
    }
}

// ---------- K4b: sum 16 partials -> ctx bf16 ----------
__global__ __launch_bounds__(256) void reduce_kernel(
    const float* __restrict__ part, unsigned short* __restrict__ ctxb)
{
  size_t i = (size_t)blockIdx.x * 256 + threadIdx.x;   // PSLICE elements
  float s = 0.f;
#pragma unroll
  for (int z = 0; z < KZ; ++z) s += part[z * PSLICE + i];
  ctxb[i] = f2bf(s);
}

// ---------- K5: out = ctx @ wo + bo (fp32 out), dbuf + counted vmcnt ----------
__global__ __launch_bounds__(512) void out_kernel(
    const unsigned short* __restrict__ ctxb, const unsigned short* __restrict__ woT,
    const float* __restrict__ bo, float* __restrict__ out)
{
  int m0 = blockIdx.x * 256;           // over MO=1640
  int n0 = blockIdx.y * 128;

  __shared__ __align__(16) struct { char A[2][32768]; char Bm[2][16384]; } sm;

  const char* Xc = (const char*)ctxb;
  const char* Wc = (const char*)woT;

  int tid  = threadIdx.x;
  int lane = tid & 63, wid = tid >> 6;
  int wr = wid >> 1, wc = wid & 1;
  int lrow = lane & 15, kseg = lane >> 4;

  f32x4 zero4 = {0.f, 0.f, 0.f, 0.f};
  f32x4 acc[4][4];
#pragma unroll
  for (int i = 0; i < 4; i++)
#pragma unroll
    for (int j = 0; j < 4; j++) acc[i][j] = zero4;

  auto stage = [&](int t, int buf) {
#pragma unroll
    for (int i = 0; i < 4; ++i) {
      int inst = wid * 4 + i;
      int sg   = inst * 64 + lane;
      int row  = sg >> 3, c16 = sg & 7;
      int m = m0 + row; m = (m > MO - 1) ? (MO - 1) : m;
      gload16(Xc + ((size_t)m << 9) + (t << 7) + ((c16 ^ (row & 7)) << 4),
              sm.A[buf] + inst * 1024);
    }
#pragma unroll
    for (int i = 0; i < 2; ++i) {
      int inst = wid * 2 + i;
      int sg   = inst * 64 + lane;
      int row  = sg >> 3, c16 = sg & 7;
      gload16(Wc + ((size_t)(n0 + row) << 9) + (t << 7) + ((c16 ^ (row & 7)) << 4),
              sm.Bm[buf] + inst * 1024);
    }
  };

  stage(0, 0);
#pragma unroll
  for (int t = 0; t < 4; ++t) {
    int cur = t & 1;
    if (t < 3) { stage(t + 1, cur ^ 1); WAIT_VM(6); } else { WAIT_VM(0); }
    barrier_mem();
    const char* Asm = sm.A[cur];
    const char* Bsm = sm.Bm[cur];
#pragma unroll
    for (int kk = 0; kk < 2; ++kk) {
      bf16x8 af[4], bfr[4];
#pragma unroll
      for (int mi = 0; mi < 4; ++mi) {
        int R = wr * 64 + mi * 16 + lrow;
        int c16 = (kk * 4 + kseg) ^ (R & 7);
        af[mi] = *reinterpret_cast<const bf16x8*>(Asm + R * 128 + c16 * 16);
      }
#pragma unroll
      for (int cf = 0; cf < 4; ++cf) {
        int nl = wc * 64 + cf * 16 + lrow;
        int c16 = (kk * 4 + kseg) ^ (nl & 7);
        bfr[cf] = *reinterpret_cast<const bf16x8*>(Bsm + nl * 128 + c16 * 16);
      }
#pragma unroll
      for (int mi = 0; mi < 4; ++mi)
#pragma unroll
        for (int cf = 0; cf < 4; ++cf)
          acc[mi][cf] = mfma16(af[mi], bfr[cf], acc[mi][cf]);
    }
    barrier_mem();
  }

  int r4 = kseg * 4;
#pragma unroll
  for (int mi = 0; mi < 4; mi++)
#pragma unroll
    for (int cf = 0; cf < 4; cf++) {
      int n = n0 + wc * 64 + cf * 16 + lrow;
      float bv_ = bo[n];
#pragma unroll
      for (int r = 0; r < 4; r++) {
        int m = m0 + wr * 64 + mi * 16 + r4 + r;
        if (m < MO) out[(size_t)m * 256 + n] = acc[mi][cf][r] + bv_;
      }
    }
}

// ---------- launch ----------
extern "C" void kernel_launch(void* const* d_in, const int* in_sizes, int n_in,
                              void* d_out, int out_size, void* d_ws, size_t ws_size,
                              hipStream_t stream)
{
  const float* v  = (const float*)d_in[0];
  const float* k  = (const float*)d_in[1];
  const float* q  = (const float*)d_in[2];
  const float* wq = (const float*)d_in[3];
  const float* bq = (const float*)d_in[4];
  const float* wk = (const float*)d_in[5];
  const float* bk = (const float*)d_in[6];
  const float* wv = (const float*)d_in[7];
  const float* bv = (const float*)d_in[8];
  const float* wo = (const float*)d_in[9];
  const float* bo = (const float*)d_in[10];
  float* out = (float*)d_out;

  char* ws = (char*)d_ws;
  size_t off = 0;
  auto alloc = [&](size_t bytes) -> void* {
    void* p = ws + off;
    off += (bytes + 255) & ~(size_t)255;
    return p;
  };
  unsigned short* qp   = (unsigned short*)alloc((size_t)B * S * D * 2);     // 8 MB
  unsigned short* kp   = (unsigned short*)alloc((size_t)B * S * D * 2);     // 8 MB
  unsigned short* vpT  = (unsigned short*)alloc((size_t)B * S * D * 2);     // 8 MB
  unsigned short* wt   = (unsigned short*)alloc((size_t)4 * 256 * 256 * 2); // 0.5 MB
  unsigned short* ctxb = (unsigned short*)alloc(PSLICE * 2);                // 0.84 MB
  // shared region (disjoint lifetimes): qx/kx/vx [cvt->proj], pooled [scores->softmax],
  // part [pv->reduce]
  char* shared_region  = (char*)alloc((size_t)B * SP * 4096 * 4);
  unsigned short* attn = (unsigned short*)alloc((size_t)B * SP * 4096 * 2); // 13.4 MB

  unsigned short* qx = (unsigned short*)shared_region;
  unsigned short* kx = qx + (size_t)B * S * D;
  unsigned short* vx = kx + (size_t)B * S * D;
  float* pooled = (float*)shared_region;
  float* part   = (float*)shared_region;

  cvtwt_kernel<<<dim3(2048, 4), 256, 0, stream>>>(q, k, v, wq, wk, wv, wo, qx, kx, vx, wt);
  proj_kernel<<<dim3(64, 2, 3), 512, 0, stream>>>(qx, kx, vx, wt, bq, bk, bv, qp, kp, vpT);
  scores_pool_kernel<<<256, 512, 0, stream>>>(qp, kp, pooled);
  softmax_kernel<<<B * SP, 256, 0, stream>>>(pooled, attn);
  pv_kernel<<<dim3(16, 2, KZ), 256, 0, stream>>>(attn, vpT, part);
  reduce_kernel<<<(int)(PSLICE / 256), 256, 0, stream>>>(part, ctxb);
  out_kernel<<<dim3(7, 2), 512, 0, stream>>>(ctxb, wt + 3 * 65536, bo, out);
}